// Round 22
// baseline (1110.317 us; speedup 1.0000x reference)
//
#include <hip/hip_runtime.h>
#include <cstdint>

typedef unsigned long long u64;
typedef unsigned int u32;

#define L_X 16000
#define NB  64
#define P1  5320   // conv1(15960) pool3
#define P2  1746   // conv2(5240) pool3
#define P3  555    // conv3(1666) pool3
#define P4  158    // conv4(475) pool3
#define C5  78     // conv5 out, no pool

// ---- exact scalar chain: A = fl(A + (bit ? -0.1f : +0.1f)), LSB-first ----
__device__ __forceinline__ void chain64(float& A, u64 u) {
    u32 w = (u32)u;
    #pragma unroll
    for (int j = 0; j < 32; ++j)
        A = __fadd_rn(A, __uint_as_float(0x3DCCCCCDu | ((w << (31 - j)) & 0x80000000u)));
    w = (u32)(u >> 32);
    #pragma unroll
    for (int j = 0; j < 32; ++j)
        A = __fadd_rn(A, __uint_as_float(0x3DCCCCCDu | ((w << (31 - j)) & 0x80000000u)));
}

// ---------------- one fused packing kernel ----------------
#define SEG0 123
#define SEG1 (SEG0 + 2624)
#define SEG2 (SEG1 + 5248)
#define SEG3 (SEG2 + 10496)
#define SEG4 (SEG3 + 10496)
#define SEG5 (SEG4 + 159744)
#define SEG6 (SEG5 + 16000)

__device__ __forceinline__ void pack_conv(const float* w, u64* wT, int t, int Co, int CIW) {
    int co = t % Co;
    int rem = t / Co;
    int h = rem % CIW;
    int k = rem / CIW;
    int CI = CIW * 64;
    u64 word = 0;
    for (int c = 0; c < 64; ++c)
        if (w[((size_t)co * CI + h * 64 + c) * 41 + k] < 0.f) word |= 1ull << c;
    wT[t] = word;
}

__global__ void pack_all(const float* __restrict__ w1, const float* __restrict__ w2,
                         const float* __restrict__ w3, const float* __restrict__ w4,
                         const float* __restrict__ w5, const float* __restrict__ fw1,
                         const float* __restrict__ fw2,
                         u64* __restrict__ w1k, u64* __restrict__ w2T,
                         u64* __restrict__ w3T, u64* __restrict__ w4T,
                         u64* __restrict__ w5T, u64* __restrict__ fw1T,
                         u64* __restrict__ fw2T) {
    int tid = blockIdx.x * blockDim.x + threadIdx.x;
    if (tid < SEG0) {
        int ci = tid % 3;
        int k = tid / 3;
        u64 word = 0;
        for (int co = 0; co < 64; ++co)
            if (w1[(co * 3 + ci) * 41 + k] < 0.f) word |= 1ull << co;
        w1k[k * 4 + ci] = word;
    } else if (tid < SEG1) {
        pack_conv(w2, w2T, tid - SEG0, 64, 1);
    } else if (tid < SEG2) {
        pack_conv(w3, w3T, tid - SEG1, 128, 1);
    } else if (tid < SEG3) {
        pack_conv(w4, w4T, tid - SEG2, 128, 2);
    } else if (tid < SEG4) {
        pack_conv(w5, w5T, tid - SEG3, 128, 2);
    } else if (tid < SEG5) {
        int t = tid - SEG4;
        int row = t & 1023;
        int j = t >> 10;
        const float* base = fw1 + (size_t)row * 9984 + j * 64;
        u64 word = 0;
        for (int c = 0; c < 64; ++c)
            if (base[c] < 0.f) word |= 1ull << c;
        fw1T[t] = word;
    } else if (tid < SEG6) {
        int t = tid - SEG5;
        int row = t % 1000;
        int j = t / 1000;
        const float* base = fw2 + (size_t)row * 1024 + j * 64;
        u64 word = 0;
        for (int c = 0; c < 64; ++c)
            if (base[c] < 0.f) word |= 1ull << c;
        fw2T[t] = word;
    }
}

__global__ void repack_a5(const u64* __restrict__ a5, u64* __restrict__ a5F) {
    int t = blockIdx.x * blockDim.x + threadIdx.x;
    if (t >= NB * 156) return;
    int j = t % 156;
    int n = t / 156;
    u64 word = 0;
    #pragma unroll
    for (int c = 0; c < 64; ++c) {
        int jj = j * 64 + c;
        int chan = jj / 78;
        int tp = jj - chan * 78;
        u64 src = a5[((size_t)n * C5 + tp) * 2 + (chan >> 6)];
        word |= ((src >> (chan & 63)) & 1ull) << c;
    }
    a5F[t] = word;
}

// ---------------- conv1 (R17 version verbatim -- 291 us measured, refcheck'd) ----------------
__global__ __launch_bounds__(64) void conv1_s(
        const float* __restrict__ x, const u64* __restrict__ w1k,
        const float* __restrict__ s0, const float* __restrict__ b0,
        const float* __restrict__ s1, const float* __restrict__ b1,
        u64* __restrict__ a1) {
    __shared__ float yl[3][232];
    __shared__ float s1l[64], b1l[64];
    int lane = threadIdx.x;
    int qb = blockIdx.x * 64;
    int n = blockIdx.y;

    #pragma unroll
    for (int ci = 0; ci < 3; ++ci) {
        float sq = (s0[ci] < 0.f) ? -0.1f : 0.1f;
        float bb = b0[ci];
        const float* xp = x + ((size_t)n * 3 + ci) * L_X;
        for (int i = lane; i < 232; i += 64) {
            int t = 3 * qb + i;
            t = (t < L_X) ? t : (L_X - 1);
            float xsb = __fadd_rn(__fmul_rn(xp[t], sq), bb);
            yl[ci][i] = __fmul_rn(xsb, 0.1f);
        }
    }
    s1l[lane] = s1[lane];
    b1l[lane] = b1[lane];
    __syncthreads();

    int q = qb + lane;
    bool valid = q < P1;
    int base = 3 * lane;
    u64 word = 0;

    #pragma unroll 1
    for (int tile = 0; tile < 4; ++tile) {
        float S[16][3];
        #pragma unroll
        for (int c = 0; c < 16; ++c)
            #pragma unroll
            for (int r = 0; r < 3; ++r) S[c][r] = 0.f;

        #pragma unroll 1
        for (int k = 0; k < 41; ++k) {
            float y0[3], y1[3], y2[3];
            #pragma unroll
            for (int r = 0; r < 3; ++r) {
                y0[r] = yl[0][base + k + r];
                y1[r] = yl[1][base + k + r];
                y2[r] = yl[2][base + k + r];
            }
            u32 t0 = (u32)(w1k[k * 4 + 0] >> (tile * 16));
            u32 t1 = (u32)(w1k[k * 4 + 1] >> (tile * 16));
            u32 t2 = (u32)(w1k[k * 4 + 2] >> (tile * 16));
            #pragma unroll
            for (int c = 0; c < 16; ++c) {
                float wf0 = __uint_as_float(0x3F800000u | (((t0 >> c) & 1u) << 31));
                float wf1 = __uint_as_float(0x3F800000u | (((t1 >> c) & 1u) << 31));
                float wf2 = __uint_as_float(0x3F800000u | (((t2 >> c) & 1u) << 31));
                #pragma unroll
                for (int r = 0; r < 3; ++r) {
                    float A = __fmul_rn(y0[r], wf0);
                    A = __fmaf_rn(y1[r], wf1, A);
                    A = __fmaf_rn(y2[r], wf2, A);
                    S[c][r] = __fadd_rn(S[c][r], A);
                }
            }
        }
        #pragma unroll
        for (int c = 0; c < 16; ++c) {
            int co = tile * 16 + c;
            float sq1 = (s1l[co] < 0.f) ? -0.1f : 0.1f;
            float bb1 = b1l[co];
            bool neg = true;
            #pragma unroll
            for (int r = 0; r < 3; ++r) {
                float pre = __fadd_rn(__fmul_rn(S[c][r], sq1), bb1);
                neg = neg && (pre < 0.f);
            }
            word |= (u64)(neg ? 1 : 0) << co;
        }
    }
    if (valid) a1[(size_t)n * P1 + q] = word;
}

// ---------------- binary conv: popcount fast path + worklist push (lane-granular fixup) ----------------
// Flagged decisions are pushed to a worklist (entry = n<<18 | q<<7 | co); the word is written
// with the exact-integer-sign guess. bfix corrects flagged bits at one LANE per decision.
// Overflow backstop: in-wave rerun (original path) for lanes whose push didn't fit.
template <int CIW, int POOLK>
__global__ void bconv_g(const u64* __restrict__ abits_in, const u64* __restrict__ wT,
                        const float* __restrict__ s, const float* __restrict__ b,
                        u64* __restrict__ abits_out, int Lin, int Lq, double G,
                        u32* __restrict__ wl, u32* __restrict__ wl_count, u32 wl_cap) {
    constexpr int BITS = 41 * CIW * 64;
    int q = blockIdx.x;
    int n = blockIdx.y;
    int co = threadIdx.x;
    int Co = blockDim.x;
    int wave = co >> 6;
    int CoW = Co >> 6;
    float sqf = (s[co] < 0.f) ? -0.1f : 0.1f;
    float bf  = b[co];
    const u64* wp = wT + co;
    const u64* ap = abits_in + ((size_t)n * Lin + (size_t)POOLK * q) * CIW;

    int pc[POOLK];
    #pragma unroll
    for (int r = 0; r < POOLK; ++r) pc[r] = 0;
    #pragma unroll 1
    for (int k = 0; k < 41; ++k) {
        u64 wk[CIW];
        #pragma unroll
        for (int h = 0; h < CIW; ++h) wk[h] = wp[((size_t)k * CIW + h) * Co];
        const u64* ak = ap + (size_t)(2 * k) * CIW;
        #pragma unroll
        for (int r = 0; r < POOLK; ++r) {
            #pragma unroll
            for (int h = 0; h < CIW; ++h)
                pc[r] += (int)__popcll(ak[r * CIW + h] ^ wk[h]);
        }
    }
    const double vv = (double)0.1f * (double)0.1f;
    double svv = (sqf < 0.f) ? -vv : vv;
    double bd = (double)bf;
    bool negr[POOLK], flagr[POOLK], nn[POOLK], need[POOLK];
    #pragma unroll
    for (int r = 0; r < POOLK; ++r) {
        double pre = (double)(BITS - 2 * pc[r]) * svv + bd;
        negr[r] = (pre < 0.0);
        flagr[r] = (fabs(pre) < G);
        nn[r] = (pre > G);
    }
    bool need_any = false;
    #pragma unroll
    for (int r = 0; r < POOLK; ++r) {
        bool other_nn = false;
        #pragma unroll
        for (int r2 = 0; r2 < POOLK; ++r2)
            if (r2 != r) other_nn = other_nn || nn[r2];
        need[r] = flagr[r] && !other_nn;
        need_any = need_any || need[r];
    }
    bool handled = false;
    if (need_any) {
        u32 idx = atomicAdd(wl_count, 1u);
        if (idx < wl_cap) {
            wl[idx] = ((u32)n << 18) | ((u32)q << 7) | (u32)co;
            handled = true;
        }
    }
    // overflow backstop (expected never): in-wave exact rerun
    #pragma unroll
    for (int r = 0; r < POOLK; ++r) {
        bool nr = need[r] && !handled;
        if (__ballot(nr) != 0ull) {
            float S = 0.f;
            #pragma unroll 1
            for (int k = 0; k < 41; ++k) {
                float A = 0.f;
                #pragma unroll
                for (int h = 0; h < CIW; ++h) {
                    u64 u = ap[(size_t)(2 * k + r) * CIW + h]
                          ^ wp[((size_t)k * CIW + h) * Co];
                    chain64(A, u);
                }
                S = __fadd_rn(S, A);
            }
            if (nr) negr[r] = (__fadd_rn(__fmul_rn(S, sqf), bf) < 0.f);
        }
    }
    bool neg = true;
    #pragma unroll
    for (int r = 0; r < POOLK; ++r) neg = neg && negr[r];
    u64 word = __ballot(neg);
    if ((co & 63) == 0) abits_out[((size_t)n * Lq + q) * CoW + wave] = word;
}

// ---------------- fixup: one lane per flagged decision ----------------
template <int CIW, int POOLK>
__global__ void bfix(const u64* __restrict__ abits_in, const u64* __restrict__ wT,
                     const float* __restrict__ s, const float* __restrict__ b,
                     u64* __restrict__ abits_out, int Lin, int Lq, double G,
                     const u32* __restrict__ wl, const u32* __restrict__ wl_count,
                     u32 wl_cap, int Co) {
    constexpr int BITS = 41 * CIW * 64;
    u32 cnt = *wl_count;
    if (cnt > wl_cap) cnt = wl_cap;
    for (u32 i = blockIdx.x * blockDim.x + threadIdx.x; i < cnt;
         i += gridDim.x * blockDim.x) {
        u32 e = wl[i];
        int co = e & 127;
        int q  = (e >> 7) & 2047;
        int n  = (int)(e >> 18);
        const u64* wp = wT + co;
        const u64* ap = abits_in + ((size_t)n * Lin + (size_t)POOLK * q) * CIW;
        float sqf = (s[co] < 0.f) ? -0.1f : 0.1f;
        float bf  = b[co];
        int pc[POOLK];
        #pragma unroll
        for (int r = 0; r < POOLK; ++r) pc[r] = 0;
        #pragma unroll 1
        for (int k = 0; k < 41; ++k) {
            u64 wk[CIW];
            #pragma unroll
            for (int h = 0; h < CIW; ++h) wk[h] = wp[((size_t)k * CIW + h) * Co];
            const u64* ak = ap + (size_t)(2 * k) * CIW;
            #pragma unroll
            for (int r = 0; r < POOLK; ++r) {
                #pragma unroll
                for (int h = 0; h < CIW; ++h)
                    pc[r] += (int)__popcll(ak[r * CIW + h] ^ wk[h]);
            }
        }
        const double vv = (double)0.1f * (double)0.1f;
        double svv = (sqf < 0.f) ? -vv : vv;
        double bd = (double)bf;
        bool negr[POOLK], flagr[POOLK], nn[POOLK];
        #pragma unroll
        for (int r = 0; r < POOLK; ++r) {
            double pre = (double)(BITS - 2 * pc[r]) * svv + bd;
            negr[r] = (pre < 0.0);
            flagr[r] = (fabs(pre) < G);
            nn[r] = (pre > G);
        }
        bool guess = true;
        #pragma unroll
        for (int r = 0; r < POOLK; ++r) guess = guess && negr[r];
        // exact chains only for needed r's (serial per lane)
        #pragma unroll 1
        for (int r = 0; r < POOLK; ++r) {
            bool other_nn = false;
            #pragma unroll
            for (int r2 = 0; r2 < POOLK; ++r2)
                if (r2 != r) other_nn = other_nn || nn[r2];
            if (flagr[r] && !other_nn) {
                float S = 0.f;
                #pragma unroll 1
                for (int k = 0; k < 41; ++k) {
                    float A = 0.f;
                    #pragma unroll
                    for (int h = 0; h < CIW; ++h) {
                        u64 u = ap[(size_t)(2 * k + r) * CIW + h]
                              ^ wp[((size_t)k * CIW + h) * Co];
                        chain64(A, u);
                    }
                    S = __fadd_rn(S, A);
                }
                negr[r] = (__fadd_rn(__fmul_rn(S, sqf), bf) < 0.f);
            }
        }
        bool truebit = true;
        #pragma unroll
        for (int r = 0; r < POOLK; ++r) truebit = truebit && negr[r];
        if (truebit != guess) {
            int wave = co >> 6;
            int CoW = Co >> 6;
            atomicXor(&abits_out[((size_t)n * Lq + q) * CoW + wave], 1ull << (co & 63));
        }
    }
}

// ---------------- fc1: single sequential chain over 9984 bits ----------------
__global__ __launch_bounds__(64) void fc1_k(
        const u64* __restrict__ a5F, const u64* __restrict__ fw1T,
        const float* __restrict__ s6, const float* __restrict__ b6,
        u64* __restrict__ y6b) {
    int g = blockIdx.x;
    int n = blockIdx.y;
    int lane = threadIdx.x;
    int row = g * 64 + lane;
    float S = 0.f;
    #pragma unroll 1
    for (int j = 0; j < 156; ++j) {
        u64 u = a5F[(size_t)n * 156 + j] ^ fw1T[(size_t)j * 1024 + row];
        chain64(S, u);
    }
    float pre = __fadd_rn(__fmul_rn(S, (s6[row] < 0.f) ? -0.1f : 0.1f), b6[row]);
    u64 word = __ballot(pre < 0.f);
    if (lane == 0) y6b[n * 16 + g] = word;
}

// ---------------- fc2: single chain over 1024 bits -> f32 out ----------------
__global__ void fc2_k(const u64* __restrict__ y6b, const u64* __restrict__ fw2T,
                      const float* __restrict__ s7, const float* __restrict__ b7,
                      float* __restrict__ out) {
    int t = blockIdx.x * blockDim.x + threadIdx.x;
    if (t >= NB * 1000) return;
    int r = t % 1000;
    int n = t / 1000;
    float S = 0.f;
    #pragma unroll 1
    for (int j = 0; j < 16; ++j) {
        u64 u = y6b[n * 16 + j] ^ fw2T[j * 1000 + r];
        chain64(S, u);
    }
    out[t] = __fadd_rn(__fmul_rn(S, (s7[r] < 0.f) ? -0.1f : 0.1f), b7[r]);
}

// ---------------- launch ----------------
extern "C" void kernel_launch(void* const* d_in, const int* in_sizes, int n_in,
                              void* d_out, int out_size, void* d_ws, size_t ws_size,
                              hipStream_t stream) {
    const float* x   = (const float*)d_in[0];
    const float* s0  = (const float*)d_in[1];
    const float* b0  = (const float*)d_in[2];
    const float* w1  = (const float*)d_in[3];
    const float* s1  = (const float*)d_in[4];
    const float* b1  = (const float*)d_in[5];
    const float* w2  = (const float*)d_in[6];
    const float* s2  = (const float*)d_in[7];
    const float* b2  = (const float*)d_in[8];
    const float* w3  = (const float*)d_in[9];
    const float* s3  = (const float*)d_in[10];
    const float* b3  = (const float*)d_in[11];
    const float* w4  = (const float*)d_in[12];
    const float* s4  = (const float*)d_in[13];
    const float* b4  = (const float*)d_in[14];
    const float* w5  = (const float*)d_in[15];
    const float* s5  = (const float*)d_in[16];
    const float* b5  = (const float*)d_in[17];
    const float* fw1 = (const float*)d_in[18];
    const float* s6  = (const float*)d_in[19];
    const float* b6  = (const float*)d_in[20];
    const float* fw2 = (const float*)d_in[21];
    const float* s7  = (const float*)d_in[22];
    const float* b7  = (const float*)d_in[23];

    u64* p = (u64*)d_ws;
    u64* w1kb = p; p += 41 * 4;
    u64* w2T  = p; p += 41 * 64;
    u64* w3T  = p; p += 41 * 128;
    u64* w4T  = p; p += 82 * 128;
    u64* w5T  = p; p += 82 * 128;
    u64* fw1T = p; p += 156 * 1024;
    u64* fw2T = p; p += 16 * 1000;
    u64* a1   = p; p += (size_t)NB * P1;
    u64* a2   = p; p += (size_t)NB * P2;
    u64* a3   = p; p += (size_t)NB * P3 * 2;
    u64* a4   = p; p += (size_t)NB * P4 * 2;
    u64* a5   = p; p += (size_t)NB * C5 * 2;
    u64* a5F  = p; p += (size_t)NB * 156;
    u64* y6b  = p; p += (size_t)NB * 16;
    // worklists + counters
    u32* cnts = (u32*)p; p += 8;             // 4 counters (padded to 64B)
    u32* wl2 = (u32*)p; p += 512 * 1024 / 2; // 512k entries (u32) = 256k u64
    u32* wl3 = (u32*)p; p += 256 * 1024 / 2;
    u32* wl4 = (u32*)p; p += 128 * 1024 / 2;
    u32* wl5 = (u32*)p; p += 32 * 1024 / 2;
    const u32 CAP2 = 512 * 1024, CAP3 = 256 * 1024, CAP4 = 128 * 1024, CAP5 = 32 * 1024;

    const double G64  = 2.0e-4;
    const double G128 = 5.0e-4;

    hipMemsetAsync(cnts, 0, 4 * sizeof(u32), stream);

    pack_all<<<(SEG6 + 255) / 256, 256, 0, stream>>>(
        w1, w2, w3, w4, w5, fw1, fw2, w1kb, w2T, w3T, w4T, w5T, fw1T, fw2T);

    conv1_s<<<dim3((P1 + 63) / 64, NB), 64, 0, stream>>>(x, w1kb, s0, b0, s1, b1, a1);

    bconv_g<1, 3><<<dim3(P2, NB), 64, 0, stream>>>(a1, w2T, s2, b2, a2, P1, P2, G64,
                                                   wl2, cnts + 0, CAP2);
    bfix<1, 3><<<256, 256, 0, stream>>>(a1, w2T, s2, b2, a2, P1, P2, G64,
                                        wl2, cnts + 0, CAP2, 64);

    bconv_g<1, 3><<<dim3(P3, NB), 128, 0, stream>>>(a2, w3T, s3, b3, a3, P2, P3, G64,
                                                    wl3, cnts + 1, CAP3);
    bfix<1, 3><<<256, 256, 0, stream>>>(a2, w3T, s3, b3, a3, P2, P3, G64,
                                        wl3, cnts + 1, CAP3, 128);

    bconv_g<2, 3><<<dim3(P4, NB), 128, 0, stream>>>(a3, w4T, s4, b4, a4, P3, P4, G128,
                                                    wl4, cnts + 2, CAP4);
    bfix<2, 3><<<256, 256, 0, stream>>>(a3, w4T, s4, b4, a4, P3, P4, G128,
                                        wl4, cnts + 2, CAP4, 128);

    bconv_g<2, 1><<<dim3(C5, NB), 128, 0, stream>>>(a4, w5T, s5, b5, a5, P4, C5, G128,
                                                    wl5, cnts + 3, CAP5);
    bfix<2, 1><<<128, 256, 0, stream>>>(a4, w5T, s5, b5, a5, P4, C5, G128,
                                        wl5, cnts + 3, CAP5, 128);

    repack_a5<<<(NB * 156 + 255) / 256, 256, 0, stream>>>(a5, a5F);
    fc1_k<<<dim3(16, NB), 64, 0, stream>>>(a5F, fw1T, s6, b6, y6b);
    fc2_k<<<(NB * 1000 + 255) / 256, 256, 0, stream>>>(y6b, fw2T, s7, b7, (float*)d_out);
}

// Round 23
// 916.092 us; speedup vs baseline: 1.2120x; 1.2120x over previous
//
#include <hip/hip_runtime.h>
#include <cstdint>

typedef unsigned long long u64;
typedef unsigned int u32;

#define L_X 16000
#define NB  64
#define P1  5320   // conv1(15960) pool3
#define P2  1746   // conv2(5240) pool3
#define P3  555    // conv3(1666) pool3
#define P4  158    // conv4(475) pool3
#define C5  78     // conv5 out, no pool

// ---- exact scalar chain: A = fl(A + (bit ? -0.1f : +0.1f)), LSB-first ----
__device__ __forceinline__ void chain64(float& A, u64 u) {
    u32 w = (u32)u;
    #pragma unroll
    for (int j = 0; j < 32; ++j)
        A = __fadd_rn(A, __uint_as_float(0x3DCCCCCDu | ((w << (31 - j)) & 0x80000000u)));
    w = (u32)(u >> 32);
    #pragma unroll
    for (int j = 0; j < 32; ++j)
        A = __fadd_rn(A, __uint_as_float(0x3DCCCCCDu | ((w << (31 - j)) & 0x80000000u)));
}

// ---------------- one fused packing kernel (identical per-element math) ----------------
#define SEG0 123
#define SEG1 (SEG0 + 2624)
#define SEG2 (SEG1 + 5248)
#define SEG3 (SEG2 + 10496)
#define SEG4 (SEG3 + 10496)
#define SEG5 (SEG4 + 159744)
#define SEG6 (SEG5 + 16000)

__device__ __forceinline__ void pack_conv(const float* w, u64* wT, int t, int Co, int CIW) {
    int co = t % Co;
    int rem = t / Co;
    int h = rem % CIW;
    int k = rem / CIW;
    int CI = CIW * 64;
    u64 word = 0;
    for (int c = 0; c < 64; ++c)
        if (w[((size_t)co * CI + h * 64 + c) * 41 + k] < 0.f) word |= 1ull << c;
    wT[t] = word;
}

__global__ void pack_all(const float* __restrict__ w1, const float* __restrict__ w2,
                         const float* __restrict__ w3, const float* __restrict__ w4,
                         const float* __restrict__ w5, const float* __restrict__ fw1,
                         const float* __restrict__ fw2,
                         u64* __restrict__ w1k, u64* __restrict__ w2T,
                         u64* __restrict__ w3T, u64* __restrict__ w4T,
                         u64* __restrict__ w5T, u64* __restrict__ fw1T,
                         u64* __restrict__ fw2T) {
    int tid = blockIdx.x * blockDim.x + threadIdx.x;
    if (tid < SEG0) {
        int ci = tid % 3;
        int k = tid / 3;
        u64 word = 0;
        for (int co = 0; co < 64; ++co)
            if (w1[(co * 3 + ci) * 41 + k] < 0.f) word |= 1ull << co;
        w1k[k * 4 + ci] = word;
    } else if (tid < SEG1) {
        pack_conv(w2, w2T, tid - SEG0, 64, 1);
    } else if (tid < SEG2) {
        pack_conv(w3, w3T, tid - SEG1, 128, 1);
    } else if (tid < SEG3) {
        pack_conv(w4, w4T, tid - SEG2, 128, 2);
    } else if (tid < SEG4) {
        pack_conv(w5, w5T, tid - SEG3, 128, 2);
    } else if (tid < SEG5) {
        int t = tid - SEG4;
        int row = t & 1023;
        int j = t >> 10;
        const float* base = fw1 + (size_t)row * 9984 + j * 64;
        u64 word = 0;
        for (int c = 0; c < 64; ++c)
            if (base[c] < 0.f) word |= 1ull << c;
        fw1T[t] = word;
    } else if (tid < SEG6) {
        int t = tid - SEG5;
        int row = t % 1000;
        int j = t / 1000;
        const float* base = fw2 + (size_t)row * 1024 + j * 64;
        u64 word = 0;
        for (int c = 0; c < 64; ++c)
            if (base[c] < 0.f) word |= 1ull << c;
        fw2T[t] = word;
    }
}

__global__ void repack_a5(const u64* __restrict__ a5, u64* __restrict__ a5F) {
    int t = blockIdx.x * blockDim.x + threadIdx.x;
    if (t >= NB * 156) return;
    int j = t % 156;
    int n = t / 156;
    u64 word = 0;
    #pragma unroll
    for (int c = 0; c < 64; ++c) {
        int jj = j * 64 + c;
        int chan = jj / 78;
        int tp = jj - chan * 78;
        u64 src = a5[((size_t)n * C5 + tp) * 2 + (chan >> 6)];
        word |= ((src >> (chan & 63)) & 1ull) << c;
    }
    a5F[t] = word;
}

// ---------------- conv1 (R17 version verbatim -- 291 us measured, refcheck'd) ----------------
__global__ __launch_bounds__(64) void conv1_s(
        const float* __restrict__ x, const u64* __restrict__ w1k,
        const float* __restrict__ s0, const float* __restrict__ b0,
        const float* __restrict__ s1, const float* __restrict__ b1,
        u64* __restrict__ a1) {
    __shared__ float yl[3][232];
    __shared__ float s1l[64], b1l[64];
    int lane = threadIdx.x;
    int qb = blockIdx.x * 64;
    int n = blockIdx.y;

    #pragma unroll
    for (int ci = 0; ci < 3; ++ci) {
        float sq = (s0[ci] < 0.f) ? -0.1f : 0.1f;
        float bb = b0[ci];
        const float* xp = x + ((size_t)n * 3 + ci) * L_X;
        for (int i = lane; i < 232; i += 64) {
            int t = 3 * qb + i;
            t = (t < L_X) ? t : (L_X - 1);
            float xsb = __fadd_rn(__fmul_rn(xp[t], sq), bb);
            yl[ci][i] = __fmul_rn(xsb, 0.1f);
        }
    }
    s1l[lane] = s1[lane];
    b1l[lane] = b1[lane];
    __syncthreads();

    int q = qb + lane;
    bool valid = q < P1;
    int base = 3 * lane;
    u64 word = 0;

    #pragma unroll 1
    for (int tile = 0; tile < 4; ++tile) {
        float S[16][3];
        #pragma unroll
        for (int c = 0; c < 16; ++c)
            #pragma unroll
            for (int r = 0; r < 3; ++r) S[c][r] = 0.f;

        #pragma unroll 1
        for (int k = 0; k < 41; ++k) {
            float y0[3], y1[3], y2[3];
            #pragma unroll
            for (int r = 0; r < 3; ++r) {
                y0[r] = yl[0][base + k + r];
                y1[r] = yl[1][base + k + r];
                y2[r] = yl[2][base + k + r];
            }
            u32 t0 = (u32)(w1k[k * 4 + 0] >> (tile * 16));
            u32 t1 = (u32)(w1k[k * 4 + 1] >> (tile * 16));
            u32 t2 = (u32)(w1k[k * 4 + 2] >> (tile * 16));
            #pragma unroll
            for (int c = 0; c < 16; ++c) {
                float wf0 = __uint_as_float(0x3F800000u | (((t0 >> c) & 1u) << 31));
                float wf1 = __uint_as_float(0x3F800000u | (((t1 >> c) & 1u) << 31));
                float wf2 = __uint_as_float(0x3F800000u | (((t2 >> c) & 1u) << 31));
                #pragma unroll
                for (int r = 0; r < 3; ++r) {
                    float A = __fmul_rn(y0[r], wf0);
                    A = __fmaf_rn(y1[r], wf1, A);
                    A = __fmaf_rn(y2[r], wf2, A);
                    S[c][r] = __fadd_rn(S[c][r], A);
                }
            }
        }
        #pragma unroll
        for (int c = 0; c < 16; ++c) {
            int co = tile * 16 + c;
            float sq1 = (s1l[co] < 0.f) ? -0.1f : 0.1f;
            float bb1 = b1l[co];
            bool neg = true;
            #pragma unroll
            for (int r = 0; r < 3; ++r) {
                float pre = __fadd_rn(__fmul_rn(S[c][r], sq1), bb1);
                neg = neg && (pre < 0.f);
            }
            word |= (u64)(neg ? 1 : 0) << co;
        }
    }
    if (valid) a1[(size_t)n * P1 + q] = word;
}

// ---------------- binary conv: popcount fast path + pool-gated exact fallback ----------------
template <int CIW, int POOLK>
__global__ void bconv_g(const u64* __restrict__ abits_in, const u64* __restrict__ wT,
                        const float* __restrict__ s, const float* __restrict__ b,
                        u64* __restrict__ abits_out, int Lin, int Lq, double G) {
    constexpr int BITS = 41 * CIW * 64;
    int q = blockIdx.x;
    int n = blockIdx.y;
    int co = threadIdx.x;
    int Co = blockDim.x;
    int wave = co >> 6;
    int CoW = Co >> 6;
    float sqf = (s[co] < 0.f) ? -0.1f : 0.1f;
    float bf  = b[co];
    const u64* wp = wT + co;
    const u64* ap = abits_in + ((size_t)n * Lin + (size_t)POOLK * q) * CIW;

    int pc[POOLK];
    #pragma unroll
    for (int r = 0; r < POOLK; ++r) pc[r] = 0;
    #pragma unroll 1
    for (int k = 0; k < 41; ++k) {
        u64 wk[CIW];
        #pragma unroll
        for (int h = 0; h < CIW; ++h) wk[h] = wp[((size_t)k * CIW + h) * Co];
        const u64* ak = ap + (size_t)(2 * k) * CIW;
        #pragma unroll
        for (int r = 0; r < POOLK; ++r) {
            #pragma unroll
            for (int h = 0; h < CIW; ++h)
                pc[r] += (int)__popcll(ak[r * CIW + h] ^ wk[h]);
        }
    }
    const double vv = (double)0.1f * (double)0.1f;
    double svv = (sqf < 0.f) ? -vv : vv;
    double bd = (double)bf;
    bool negr[POOLK], flagr[POOLK], nn[POOLK];
    #pragma unroll
    for (int r = 0; r < POOLK; ++r) {
        double pre = (double)(BITS - 2 * pc[r]) * svv + bd;
        negr[r] = (pre < 0.0);
        flagr[r] = (fabs(pre) < G);
        nn[r] = (pre > G);           // robustly non-negative
    }
    #pragma unroll
    for (int r = 0; r < POOLK; ++r) {
        bool other_nn = false;
        #pragma unroll
        for (int r2 = 0; r2 < POOLK; ++r2)
            if (r2 != r) other_nn = other_nn || nn[r2];
        bool need = flagr[r] && !other_nn;
        if (__ballot(need) != 0ull) {
            float S = 0.f;
            #pragma unroll 1
            for (int k = 0; k < 41; ++k) {
                float A = 0.f;
                #pragma unroll
                for (int h = 0; h < CIW; ++h) {
                    u64 u = ap[(size_t)(2 * k + r) * CIW + h]
                          ^ wp[((size_t)k * CIW + h) * Co];
                    chain64(A, u);
                }
                S = __fadd_rn(S, A);
            }
            negr[r] = (__fadd_rn(__fmul_rn(S, sqf), bf) < 0.f);
        }
    }
    bool neg = true;
    #pragma unroll
    for (int r = 0; r < POOLK; ++r) neg = neg && negr[r];
    u64 word = __ballot(neg);
    if ((co & 63) == 0) abits_out[((size_t)n * Lq + q) * CoW + wave] = word;
}

// ---------------- fc1: single sequential chain over 9984 bits ----------------
__global__ __launch_bounds__(64) void fc1_k(
        const u64* __restrict__ a5F, const u64* __restrict__ fw1T,
        const float* __restrict__ s6, const float* __restrict__ b6,
        u64* __restrict__ y6b) {
    int g = blockIdx.x;
    int n = blockIdx.y;
    int lane = threadIdx.x;
    int row = g * 64 + lane;
    float S = 0.f;
    #pragma unroll 1
    for (int j = 0; j < 156; ++j) {
        u64 u = a5F[(size_t)n * 156 + j] ^ fw1T[(size_t)j * 1024 + row];
        chain64(S, u);
    }
    float pre = __fadd_rn(__fmul_rn(S, (s6[row] < 0.f) ? -0.1f : 0.1f), b6[row]);
    u64 word = __ballot(pre < 0.f);
    if (lane == 0) y6b[n * 16 + g] = word;
}

// ---------------- fc2: single chain over 1024 bits -> f32 out ----------------
__global__ void fc2_k(const u64* __restrict__ y6b, const u64* __restrict__ fw2T,
                      const float* __restrict__ s7, const float* __restrict__ b7,
                      float* __restrict__ out) {
    int t = blockIdx.x * blockDim.x + threadIdx.x;
    if (t >= NB * 1000) return;
    int r = t % 1000;
    int n = t / 1000;
    float S = 0.f;
    #pragma unroll 1
    for (int j = 0; j < 16; ++j) {
        u64 u = y6b[n * 16 + j] ^ fw2T[j * 1000 + r];
        chain64(S, u);
    }
    out[t] = __fadd_rn(__fmul_rn(S, (s7[r] < 0.f) ? -0.1f : 0.1f), b7[r]);
}

// ---------------- launch ----------------
extern "C" void kernel_launch(void* const* d_in, const int* in_sizes, int n_in,
                              void* d_out, int out_size, void* d_ws, size_t ws_size,
                              hipStream_t stream) {
    const float* x   = (const float*)d_in[0];
    const float* s0  = (const float*)d_in[1];
    const float* b0  = (const float*)d_in[2];
    const float* w1  = (const float*)d_in[3];
    const float* s1  = (const float*)d_in[4];
    const float* b1  = (const float*)d_in[5];
    const float* w2  = (const float*)d_in[6];
    const float* s2  = (const float*)d_in[7];
    const float* b2  = (const float*)d_in[8];
    const float* w3  = (const float*)d_in[9];
    const float* s3  = (const float*)d_in[10];
    const float* b3  = (const float*)d_in[11];
    const float* w4  = (const float*)d_in[12];
    const float* s4  = (const float*)d_in[13];
    const float* b4  = (const float*)d_in[14];
    const float* w5  = (const float*)d_in[15];
    const float* s5  = (const float*)d_in[16];
    const float* b5  = (const float*)d_in[17];
    const float* fw1 = (const float*)d_in[18];
    const float* s6  = (const float*)d_in[19];
    const float* b6  = (const float*)d_in[20];
    const float* fw2 = (const float*)d_in[21];
    const float* s7  = (const float*)d_in[22];
    const float* b7  = (const float*)d_in[23];

    u64* p = (u64*)d_ws;
    u64* w1kb = p; p += 41 * 4;
    u64* w2T  = p; p += 41 * 64;
    u64* w3T  = p; p += 41 * 128;
    u64* w4T  = p; p += 82 * 128;
    u64* w5T  = p; p += 82 * 128;
    u64* fw1T = p; p += 156 * 1024;
    u64* fw2T = p; p += 16 * 1000;
    u64* a1   = p; p += (size_t)NB * P1;
    u64* a2   = p; p += (size_t)NB * P2;
    u64* a3   = p; p += (size_t)NB * P3 * 2;
    u64* a4   = p; p += (size_t)NB * P4 * 2;
    u64* a5   = p; p += (size_t)NB * C5 * 2;
    u64* a5F  = p; p += (size_t)NB * 156;
    u64* y6b  = p; p += (size_t)NB * 16;

    // Rigorous |chain - exact| bounds (Sigma |partial| * 2^-24 model):
    // CI=64: delta_pre <= 8.6e-5 -> G64 = 1.1e-4 (28% margin)
    // CI=128: delta_pre <= 2.75e-4 -> G128 = 3.2e-4 (16% margin)
    const double G64  = 1.1e-4;
    const double G128 = 3.2e-4;

    pack_all<<<(SEG6 + 255) / 256, 256, 0, stream>>>(
        w1, w2, w3, w4, w5, fw1, fw2, w1kb, w2T, w3T, w4T, w5T, fw1T, fw2T);

    conv1_s<<<dim3((P1 + 63) / 64, NB), 64, 0, stream>>>(x, w1kb, s0, b0, s1, b1, a1);
    bconv_g<1, 3><<<dim3(P2, NB), 64, 0, stream>>>(a1, w2T, s2, b2, a2, P1, P2, G64);
    bconv_g<1, 3><<<dim3(P3, NB), 128, 0, stream>>>(a2, w3T, s3, b3, a3, P2, P3, G64);
    bconv_g<2, 3><<<dim3(P4, NB), 128, 0, stream>>>(a3, w4T, s4, b4, a4, P3, P4, G128);
    bconv_g<2, 1><<<dim3(C5, NB), 128, 0, stream>>>(a4, w5T, s5, b5, a5, P4, C5, G128);
    repack_a5<<<(NB * 156 + 255) / 256, 256, 0, stream>>>(a5, a5F);
    fc1_k<<<dim3(16, NB), 64, 0, stream>>>(a5F, fw1T, s6, b6, y6b);
    fc2_k<<<(NB * 1000 + 255) / 256, 256, 0, stream>>>(y6b, fw2T, s7, b7, (float*)d_out);
}